// Round 7
// baseline (195.831 us; speedup 1.0000x reference)
//
#include <hip/hip_runtime.h>
#include <hip/hip_bf16.h>

#define B_ 2
#define S_ 2048
#define D_ 1024
#define H_ 16
#define DH 64
#define M_ (B_*S_)   // 4096
#define NT_ (S_/64)  // 32 q tiles per (b,h)

using bf16x8 = __attribute__((ext_vector_type(8))) __bf16;
using f32x4  = __attribute__((ext_vector_type(4))) float;

// swizzle key: varies with row bits 0..2 AND 3..5 (element units, flips the
// 16B-block index within a 64-elem group)
__device__ __forceinline__ int swz(int row) { return ((row ^ (row >> 3)) & 7) << 3; }

__device__ __forceinline__ void glds16(const __bf16* g, __bf16* l) {
#if __has_builtin(__builtin_amdgcn_global_load_lds)
  __builtin_amdgcn_global_load_lds(
      (const __attribute__((address_space(1))) unsigned int*)g,
      (__attribute__((address_space(3))) unsigned int*)l, 16, 0, 0);
#else
  *(bf16x8*)l = *(const bf16x8*)g;
#endif
}

// ---------- convert x fp32 -> bf16, pre-swizzled within 64-col k-groups ----
__global__ __launch_bounds__(256) void conv_x(const float* __restrict__ x,
                                              __bf16* __restrict__ xb) {
  int idx = blockIdx.x * 256 + threadIdx.x;
  int m = idx >> 7, k = (idx & 127) * 8;
  float4 a = *(const float4*)&x[(size_t)m * D_ + k];
  float4 b = *(const float4*)&x[(size_t)m * D_ + k + 4];
  bf16x8 o;
  o[0]=(__bf16)a.x; o[1]=(__bf16)a.y; o[2]=(__bf16)a.z; o[3]=(__bf16)a.w;
  o[4]=(__bf16)b.x; o[5]=(__bf16)b.y; o[6]=(__bf16)b.z; o[7]=(__bf16)b.w;
  *(bf16x8*)&xb[(size_t)m * D_ + (k & ~63) + ((k & 63) ^ swz(m))] = o;
}

// ---------- transpose+convert W [k][n] fp32 -> Wt [n][k] bf16 (pre-swz) ----
__global__ __launch_bounds__(256) void conv_w(const float* __restrict__ Wq,
                                              const float* __restrict__ Wk,
                                              const float* __restrict__ Wv,
                                              __bf16* __restrict__ wt) {
  int z = blockIdx.z;
  const float* __restrict__ W = (z == 0) ? Wq : (z == 1) ? Wk : Wv;
  __bf16* __restrict__ Wt = wt + (size_t)z * D_ * D_;
  __shared__ __bf16 Lt[64 * 66];
  int tid = threadIdx.x;
  int k0 = blockIdx.x * 64, n0 = blockIdx.y * 64;
  #pragma unroll
  for (int i = 0; i < 4; ++i) {
    int f4 = i * 256 + tid;
    int r = f4 >> 4, c4 = (f4 & 15) * 4;
    float4 v = *(const float4*)&W[(size_t)(k0 + r) * D_ + n0 + c4];
    Lt[(c4 + 0) * 66 + r] = (__bf16)v.x;
    Lt[(c4 + 1) * 66 + r] = (__bf16)v.y;
    Lt[(c4 + 2) * 66 + r] = (__bf16)v.z;
    Lt[(c4 + 3) * 66 + r] = (__bf16)v.w;
  }
  __syncthreads();
  #pragma unroll
  for (int i = 0; i < 2; ++i) {
    int idx = i * 256 + tid;
    int n = idx >> 3, kc = (idx & 7) * 8;
    int nf = n0 + n;
    bf16x8 o;
    #pragma unroll
    for (int j = 0; j < 8; ++j) o[j] = Lt[n * 66 + kc + j];
    *(bf16x8*)&Wt[(size_t)nf * D_ + k0 + (kc ^ swz(nf))] = o;
  }
}

// ---------- QKV GEMM: 128x128 tile, BK=64, 4 waves, 2-phase LDS dbuf -------
// grid (8,32,3) = 768 blocks = 3/CU, 64KB LDS -> 2 resident blocks/CU.
#define BK 64
#define NKT (D_/BK)  // 16

__global__ __launch_bounds__(256) void qkv_gemm(
    const __bf16* __restrict__ xb, const __bf16* __restrict__ wt,
    const float* __restrict__ bq, const float* __restrict__ bk,
    const float* __restrict__ bv, __bf16* __restrict__ qkv) {
  int z = blockIdx.z;
  const __bf16* __restrict__ Wt = wt + (size_t)z * D_ * D_;
  const float* __restrict__ bias = (z == 0) ? bq : (z == 1) ? bk : bv;
  __bf16* __restrict__ out = qkv + (size_t)z * M_ * D_;
  // Q gets 1/sqrt(dh) * log2(e) so attention softmax runs in exp2 domain
  const float scale = (z == 0) ? 0.18033688f : 1.0f;

  __shared__ __bf16 Al[2][128 * 64];  // 2 x 16KB
  __shared__ __bf16 Bl[2][128 * 64];  // 2 x 16KB

  int tid = threadIdx.x, lane = tid & 63, w = tid >> 6;  // 4 waves
  int m0 = blockIdx.y * 128, n0 = blockIdx.x * 128;
  int wr = (w >> 1) * 64, wc = (w & 1) * 64;

  f32x4 acc[4][4] = {};

#define STAGE(buf, kt)                                                        \
  {                                                                           \
    int k0 = (kt) * BK;                                                       \
    _Pragma("unroll")                                                         \
    for (int r = 0; r < 4; ++r) {                                             \
      int e = (r * 256 + tid) * 8;                                            \
      int row = e >> 6, col = e & 63;                                         \
      glds16(&xb[(size_t)(m0 + row) * D_ + k0 + col], &Al[buf][e]);           \
      glds16(&Wt[(size_t)(n0 + row) * D_ + k0 + col], &Bl[buf][e]);           \
    }                                                                         \
  }

  STAGE(0, 0);
  __syncthreads();

  int cur = 0;
  for (int kt = 0; kt < NKT; ++kt) {
    if (kt + 1 < NKT) STAGE(cur ^ 1, kt + 1);   // next tile flies under compute
    #pragma unroll
    for (int kk = 0; kk < 2; ++kk) {
      bf16x8 af[4], bfr[4];
      #pragma unroll
      for (int mi = 0; mi < 4; ++mi) {
        int row = wr + mi * 16 + (lane & 15);
        af[mi] = *(const bf16x8*)&Al[cur][row * 64 +
                 ((kk * 32 + (lane >> 4) * 8) ^ swz(row))];
      }
      #pragma unroll
      for (int ni = 0; ni < 4; ++ni) {
        int col = wc + ni * 16 + (lane & 15);
        bfr[ni] = *(const bf16x8*)&Bl[cur][col * 64 +
                  ((kk * 32 + (lane >> 4) * 8) ^ swz(col))];
      }
      #pragma unroll
      for (int mi = 0; mi < 4; ++mi)
        #pragma unroll
        for (int ni = 0; ni < 4; ++ni)
          acc[mi][ni] = __builtin_amdgcn_mfma_f32_16x16x32_bf16(
              af[mi], bfr[ni], acc[mi][ni], 0, 0, 0);
    }
    __syncthreads();   // drains next-tile loads; all done reading cur
    cur ^= 1;
  }
#undef STAGE

  #pragma unroll
  for (int mi = 0; mi < 4; ++mi) {
    #pragma unroll
    for (int ni = 0; ni < 4; ++ni) {
      int col = n0 + wc + ni * 16 + (lane & 15);
      int h = col >> 6, dh = col & 63;
      float bv_ = bias[col];
      #pragma unroll
      for (int r = 0; r < 4; ++r) {
        int row = m0 + wr + mi * 16 + (lane >> 4) * 4 + r;
        int b = row >> 11, s = row & 2047;
        out[((size_t)(b * H_ + h) * S_ + s) * DH + dh] =
            (__bf16)((acc[mi][ni][r] + bv_) * scale);
      }
    }
  }
}

// ---------- V transpose: [b][h][s][dh] -> [b][h][dh][s] --------------------
__global__ __launch_bounds__(256) void vtrans(const __bf16* __restrict__ v,
                                              __bf16* __restrict__ vt) {
  __shared__ __bf16 Lt[64 * 64];
  int tid = threadIdx.x;
  int s0 = blockIdx.x * 64;
  int h = blockIdx.y, b = blockIdx.z;
  const __bf16* __restrict__ src = v + ((size_t)(b * H_ + h)) * S_ * DH;
  __bf16* __restrict__ dst = vt + ((size_t)(b * H_ + h)) * DH * S_;
  #pragma unroll
  for (int i = 0; i < 2; ++i) {
    int e = (i * 256 + tid) * 8;
    int s = e >> 6, d0 = e & 63;
    bf16x8 r = *(const bf16x8*)&src[(size_t)(s0 + s) * DH + d0];
    #pragma unroll
    for (int j = 0; j < 8; ++j) {
      int d = d0 + j;
      Lt[d * 64 + (s ^ swz(d))] = r[j];
    }
  }
  __syncthreads();
  #pragma unroll
  for (int i = 0; i < 2; ++i) {
    int e = (i * 256 + tid) * 8;
    int d = e >> 6, sc = e & 63;
    bf16x8 o = *(const bf16x8*)&Lt[d * 64 + (sc ^ swz(d))];
    *(bf16x8*)&dst[(size_t)d * S_ + s0 + sc] = o;
  }
}

// ---------- flash attention: swapped QK^T, exp2 softmax, defer-max ---------
// S^T = mfma(A=K, B=Q): lane owns q-col = lane&15, kv rows g*4+r per frag.
// Scores arrive pre-scaled by log2(e)/sqrt(dh); softmax uses exp2 throughout.
__device__ __forceinline__ void attn_tile_sw(
    const bf16x8* aq, f32x4* accO, float& m_reg, float& l_reg,
    const __bf16* __restrict__ Kl, const __bf16* __restrict__ Vt,
    __bf16* __restrict__ Plw, int lane, int kv0, int qbase, bool diag) {
  const int g = lane >> 4;      // 0..3
  const int ql = lane & 15;
  f32x4 sfT[4];
  __builtin_amdgcn_s_setprio(1);
  #pragma unroll
  for (int f = 0; f < 4; ++f) {
    f32x4 zz = {};
    int row = f * 16 + ql;      // kv row of K
    int sr = swz(row);
    #pragma unroll
    for (int kk = 0; kk < 2; ++kk) {
      bf16x8 ka = *(const bf16x8*)&Kl[row * 64 + ((kk * 32 + g * 8) ^ sr)];
      zz = __builtin_amdgcn_mfma_f32_16x16x32_bf16(ka, aq[kk], zz, 0, 0, 0);
    }
    sfT[f] = zz;
  }
  __builtin_amdgcn_s_setprio(0);

  if (diag) {
    int qg = qbase + ql;
    #pragma unroll
    for (int f = 0; f < 4; ++f)
      #pragma unroll
      for (int r = 0; r < 4; ++r)
        if (kv0 + f * 16 + g * 4 + r > qg) sfT[f][r] = -1e30f;
  }

  // per-q tile max: 16 in-lane + 2-step butterfly (q = ql lives per-lane)
  float mx = fmaxf(fmaxf(sfT[0][0], sfT[0][1]), fmaxf(sfT[0][2], sfT[0][3]));
  #pragma unroll
  for (int f = 1; f < 4; ++f)
    mx = fmaxf(mx, fmaxf(fmaxf(sfT[f][0], sfT[f][1]),
                         fmaxf(sfT[f][2], sfT[f][3])));
  mx = fmaxf(mx, __shfl_xor(mx, 16, 64));
  mx = fmaxf(mx, __shfl_xor(mx, 32, 64));

  // defer-max (T13, log2 domain): only rescale when max grew past 2^11.54
  if (!__all(mx <= m_reg + 11.54f)) {
    float mnew = fmaxf(m_reg, mx);
    float alpha = exp2f(m_reg - mnew);
    m_reg = mnew;
    float ab[4];
    #pragma unroll
    for (int r = 0; r < 4; ++r) ab[r] = __shfl(alpha, g * 4 + r, 16);
    #pragma unroll
    for (int f = 0; f < 4; ++f)
      #pragma unroll
      for (int r = 0; r < 4; ++r) accO[f][r] *= ab[r];
    l_reg *= alpha;
  }

  float rs = 0.f;
  #pragma unroll
  for (int f = 0; f < 4; ++f)
    #pragma unroll
    for (int r = 0; r < 4; ++r) {
      float p = exp2f(sfT[f][r] - m_reg);
      sfT[f][r] = p;
      rs += p;
    }
  rs += __shfl_xor(rs, 16, 64);
  rs += __shfl_xor(rs, 32, 64);
  l_reg += rs;

  // packed P write: v_cvt_pk_bf16_f32 pairs -> 8 x ds_write_b32
  const int key = (ql & 7) << 3;
  #pragma unroll
  for (int f = 0; f < 4; ++f)
    #pragma unroll
    for (int rp = 0; rp < 2; ++rp) {
      unsigned u;
      asm volatile("v_cvt_pk_bf16_f32 %0, %1, %2"
                   : "=v"(u) : "v"(sfT[f][2 * rp]), "v"(sfT[f][2 * rp + 1]));
      *(unsigned*)&Plw[ql * 64 + ((f * 16 + g * 4 + 2 * rp) ^ key)] = u;
    }

  // O += P V : A = P rows (q=lane&15), B = V^T rows (dh=lane&15)
  __builtin_amdgcn_s_setprio(1);
  #pragma unroll
  for (int kk = 0; kk < 2; ++kk) {
    bf16x8 pa = *(const bf16x8*)&Plw[ql * 64 + ((kk * 32 + g * 8) ^ key)];
    #pragma unroll
    for (int f = 0; f < 4; ++f) {
      int vrow = f * 16 + ql;
      bf16x8 vb = *(const bf16x8*)&Vt[vrow * 64 + ((kk * 32 + g * 8) ^ swz(vrow))];
      accO[f] = __builtin_amdgcn_mfma_f32_16x16x32_bf16(pa, vb, accO[f], 0, 0, 0);
    }
  }
  __builtin_amdgcn_s_setprio(0);
}

__device__ __forceinline__ void attn_out_sw(
    const f32x4* accO, float l_reg, float* __restrict__ out,
    int b, int h, int qbase, int lane) {
  float lr[4];
  #pragma unroll
  for (int r = 0; r < 4; ++r) lr[r] = __shfl(l_reg, (lane >> 4) * 4 + r, 16);
  #pragma unroll
  for (int f = 0; f < 4; ++f) {
    int dh = f * 16 + (lane & 15);
    #pragma unroll
    for (int r = 0; r < 4; ++r) {
      int qg = qbase + (lane >> 4) * 4 + r;
      out[((size_t)(b * S_ + qg)) * D_ + h * DH + dh] = accO[f][r] / lr[r];
    }
  }
}

__global__ __launch_bounds__(256) void attn(
    const __bf16* __restrict__ Q, const __bf16* __restrict__ K,
    const __bf16* __restrict__ VT, float* __restrict__ out) {
  __shared__ __bf16 Kl[64 * 64];     // [kv][dh], swizzled
  __shared__ __bf16 Vt[64 * 64];     // [dh][kv], swizzled
  __shared__ __bf16 Pl[4][16 * 64];  // per-wave P

  int tid = threadIdx.x, lane = tid & 63, w = tid >> 6;
  int bx = blockIdx.x, h = blockIdx.y, b = blockIdx.z;
  int qA0 = bx * 64, qB0 = (NT_ - 1 - bx) * 64;   // paired tiles: i and 31-i
  size_t base = ((size_t)(b * H_ + h)) * S_ * DH;
  const __bf16* __restrict__ Qg = Q + base;
  const __bf16* __restrict__ Kg = K + base;
  const __bf16* __restrict__ VTg = VT + base;     // [dh][s]

  bf16x8 aqA[2], aqB[2];
  int qra = qA0 + w * 16 + (lane & 15), qrb = qB0 + w * 16 + (lane & 15);
  #pragma unroll
  for (int kk = 0; kk < 2; ++kk) {
    aqA[kk] = *(const bf16x8*)&Qg[(size_t)qra * DH + kk * 32 + (lane >> 4) * 8];
    aqB[kk] = *(const bf16x8*)&Qg[(size_t)qrb * DH + kk * 32 + (lane >> 4) * 8];
  }

  f32x4 accA[4] = {}, accB[4] = {};
  float mA = -1e30f, lA = 0.f, mB = -1e30f, lB = 0.f;

  const int ktA = bx, ktB = NT_ - 1 - bx;

  // prologue: prefetch tile 0 into regs
  bf16x8 kreg[2], vreg[2];
  #pragma unroll
  for (int i = 0; i < 2; ++i) {
    int e = (i * 256 + tid) * 8;
    kreg[i] = *(const bf16x8*)&Kg[(size_t)(e >> 6) * DH + (e & 63)];
    vreg[i] = *(const bf16x8*)&VTg[(size_t)(e >> 6) * S_ + (e & 63)];
  }

  for (int kt = 0; kt <= ktB; ++kt) {
    int kv0 = kt * 64;
    // staged regs -> LDS, both vectorized b128
    #pragma unroll
    for (int i = 0; i < 2; ++i) {
      int e = (i * 256 + tid) * 8;
      int rrow = e >> 6, cc = e & 63;
      *(bf16x8*)&Kl[rrow * 64 + (cc ^ swz(rrow))] = kreg[i];
      *(bf16x8*)&Vt[rrow * 64 + (cc ^ swz(rrow))] = vreg[i];
    }
    __syncthreads();

    // prefetch next tile; loads fly under compute
    if (kt < ktB) {
      int kvn = kv0 + 64;
      #pragma unroll
      for (int i = 0; i < 2; ++i) {
        int e = (i * 256 + tid) * 8;
        kreg[i] = *(const bf16x8*)&Kg[(size_t)(kvn + (e >> 6)) * DH + (e & 63)];
        vreg[i] = *(const bf16x8*)&VTg[(size_t)(e >> 6) * S_ + kvn + (e & 63)];
      }
    }

    attn_tile_sw(aqB, accB, mB, lB, Kl, Vt, Pl[w], lane, kv0, qB0 + w * 16,
                 kt == ktB);
    if (kt <= ktA)
      attn_tile_sw(aqA, accA, mA, lA, Kl, Vt, Pl[w], lane, kv0, qA0 + w * 16,
                   kt == ktA);
    __syncthreads();
  }

  attn_out_sw(accA, lA, out, b, h, qA0 + w * 16, lane);
  attn_out_sw(accB, lB, out, b, h, qB0 + w * 16, lane);
}

extern "C" void kernel_launch(void* const* d_in, const int* in_sizes, int n_in,
                              void* d_out, int out_size, void* d_ws, size_t ws_size,
                              hipStream_t stream) {
  const float* x  = (const float*)d_in[0];
  const float* Wq = (const float*)d_in[1];
  const float* bq = (const float*)d_in[2];
  const float* Wk = (const float*)d_in[3];
  const float* bk = (const float*)d_in[4];
  const float* Wv = (const float*)d_in[5];
  const float* bv = (const float*)d_in[6];
  float* out = (float*)d_out;

  __bf16* xb  = (__bf16*)d_ws;             // 8 MB (reused as vt after gemm)
  __bf16* wt  = xb + (size_t)M_ * D_;      // 6 MB
  __bf16* qkv = wt + (size_t)3 * D_ * D_;  // 24 MB
  __bf16* wsq = qkv;
  __bf16* wsk = qkv + (size_t)M_ * D_;
  __bf16* wsv = qkv + (size_t)2 * M_ * D_;
  __bf16* vtg = xb;                        // xb dead after qkv_gemm; same size

  conv_x<<<(M_ * (D_ / 8)) / 256, 256, 0, stream>>>(x, xb);
  conv_w<<<dim3(D_ / 64, D_ / 64, 3), 256, 0, stream>>>(Wq, Wk, Wv, wt);
  qkv_gemm<<<dim3(D_ / 128, M_ / 128, 3), 256, 0, stream>>>(xb, wt, bq, bk, bv, qkv);
  vtrans<<<dim3(S_ / 64, H_, B_), 256, 0, stream>>>(wsv, vtg);
  attn<<<dim3(NT_ / 2, H_, B_), 256, 0, stream>>>(wsq, wsk, vtg, out);
}

// Round 8
// 193.559 us; speedup vs baseline: 1.0117x; 1.0117x over previous
//
#include <hip/hip_runtime.h>
#include <hip/hip_bf16.h>

#define B_ 2
#define S_ 2048
#define D_ 1024
#define H_ 16
#define DH 64
#define M_ (B_*S_)   // 4096
#define NT_ (S_/64)  // 32 q tiles per (b,h)

using bf16x8 = __attribute__((ext_vector_type(8))) __bf16;
using f32x4  = __attribute__((ext_vector_type(4))) float;

__device__ __forceinline__ int swz(int row) { return ((row ^ (row >> 3)) & 7) << 3; }

__device__ __forceinline__ void glds16(const __bf16* g, __bf16* l) {
#if __has_builtin(__builtin_amdgcn_global_load_lds)
  __builtin_amdgcn_global_load_lds(
      (const __attribute__((address_space(1))) unsigned int*)g,
      (__attribute__((address_space(3))) unsigned int*)l, 16, 0, 0);
#else
  *(bf16x8*)l = *(const bf16x8*)g;
#endif
}

// ---------- convert x fp32 -> bf16, pre-swizzled within 64-col k-groups ----
__global__ __launch_bounds__(256) void conv_x(const float* __restrict__ x,
                                              __bf16* __restrict__ xb) {
  int idx = blockIdx.x * 256 + threadIdx.x;
  int m = idx >> 7, k = (idx & 127) * 8;
  float4 a = *(const float4*)&x[(size_t)m * D_ + k];
  float4 b = *(const float4*)&x[(size_t)m * D_ + k + 4];
  bf16x8 o;
  o[0]=(__bf16)a.x; o[1]=(__bf16)a.y; o[2]=(__bf16)a.z; o[3]=(__bf16)a.w;
  o[4]=(__bf16)b.x; o[5]=(__bf16)b.y; o[6]=(__bf16)b.z; o[7]=(__bf16)b.w;
  *(bf16x8*)&xb[(size_t)m * D_ + (k & ~63) + ((k & 63) ^ swz(m))] = o;
}

// ---------- transpose+convert W [k][n] fp32 -> Wt [n][k] bf16 (pre-swz) ----
__global__ __launch_bounds__(256) void conv_w(const float* __restrict__ Wq,
                                              const float* __restrict__ Wk,
                                              const float* __restrict__ Wv,
                                              __bf16* __restrict__ wt) {
  int z = blockIdx.z;
  const float* __restrict__ W = (z == 0) ? Wq : (z == 1) ? Wk : Wv;
  __bf16* __restrict__ Wt = wt + (size_t)z * D_ * D_;
  __shared__ __bf16 Lt[64 * 66];
  int tid = threadIdx.x;
  int k0 = blockIdx.x * 64, n0 = blockIdx.y * 64;
  #pragma unroll
  for (int i = 0; i < 4; ++i) {
    int f4 = i * 256 + tid;
    int r = f4 >> 4, c4 = (f4 & 15) * 4;
    float4 v = *(const float4*)&W[(size_t)(k0 + r) * D_ + n0 + c4];
    Lt[(c4 + 0) * 66 + r] = (__bf16)v.x;
    Lt[(c4 + 1) * 66 + r] = (__bf16)v.y;
    Lt[(c4 + 2) * 66 + r] = (__bf16)v.z;
    Lt[(c4 + 3) * 66 + r] = (__bf16)v.w;
  }
  __syncthreads();
  #pragma unroll
  for (int i = 0; i < 2; ++i) {
    int idx = i * 256 + tid;
    int n = idx >> 3, kc = (idx & 7) * 8;
    int nf = n0 + n;
    bf16x8 o;
    #pragma unroll
    for (int j = 0; j < 8; ++j) o[j] = Lt[n * 66 + kc + j];
    *(bf16x8*)&Wt[(size_t)nf * D_ + k0 + (kc ^ swz(nf))] = o;
  }
}

// ---------- QKV GEMM: 256x256 tile, BK=64, 8 waves, 2-phase LDS dbuf -------
#define BM 256
#define BN 256
#define BK 64
#define NKT (D_/BK)  // 16

__global__ __launch_bounds__(512) void qkv_gemm(
    const __bf16* __restrict__ xb, const __bf16* __restrict__ wt,
    const float* __restrict__ bq, const float* __restrict__ bk,
    const float* __restrict__ bv, __bf16* __restrict__ qkv) {
  int z = blockIdx.z;
  const __bf16* __restrict__ Wt = wt + (size_t)z * D_ * D_;
  const float* __restrict__ bias = (z == 0) ? bq : (z == 1) ? bk : bv;
  __bf16* __restrict__ out = qkv + (size_t)z * M_ * D_;
  // Q gets 1/sqrt(dh) * log2(e): attention softmax runs in exp2 domain
  const float scale = (z == 0) ? 0.18033688f : 1.0f;

  __shared__ __bf16 Al[2][BM * BK];
  __shared__ __bf16 Bl[2][BM * BK];

  int tid = threadIdx.x, lane = tid & 63, w = tid >> 6;
  int m0 = blockIdx.y * BM, n0 = blockIdx.x * BN;
  int wr = (w >> 2) * 128;
  int wc = (w & 3) * 64;

  f32x4 acc[8][4] = {};

#define STAGE(buf, kt)                                                        \
  {                                                                           \
    int k0 = (kt) * BK;                                                       \
    _Pragma("unroll")                                                         \
    for (int r = 0; r < 4; ++r) {                                             \
      int e = (r * 512 + tid) * 8;                                            \
      int row = e >> 6, col = e & 63;                                         \
      glds16(&xb[(size_t)(m0 + row) * D_ + k0 + col], &Al[buf][e]);           \
      glds16(&Wt[(size_t)(n0 + row) * D_ + k0 + col], &Bl[buf][e]);           \
    }                                                                         \
  }

  STAGE(0, 0);
  __syncthreads();

  int cur = 0;
  for (int kt = 0; kt < NKT; ++kt) {
    if (kt + 1 < NKT) STAGE(cur ^ 1, kt + 1);
    #pragma unroll
    for (int kk = 0; kk < 2; ++kk) {
      bf16x8 af[8], bfr[4];
      #pragma unroll
      for (int mi = 0; mi < 8; ++mi) {
        int row = wr + mi * 16 + (lane & 15);
        af[mi] = *(const bf16x8*)&Al[cur][row * 64 +
                 ((kk * 32 + (lane >> 4) * 8) ^ swz(row))];
      }
      #pragma unroll
      for (int ni = 0; ni < 4; ++ni) {
        int col = wc + ni * 16 + (lane & 15);
        bfr[ni] = *(const bf16x8*)&Bl[cur][col * 64 +
                  ((kk * 32 + (lane >> 4) * 8) ^ swz(col))];
      }
      #pragma unroll
      for (int mi = 0; mi < 8; ++mi)
        #pragma unroll
        for (int ni = 0; ni < 4; ++ni)
          acc[mi][ni] = __builtin_amdgcn_mfma_f32_16x16x32_bf16(
              af[mi], bfr[ni], acc[mi][ni], 0, 0, 0);
    }
    __syncthreads();
    cur ^= 1;
  }
#undef STAGE

  #pragma unroll
  for (int mi = 0; mi < 8; ++mi) {
    #pragma unroll
    for (int ni = 0; ni < 4; ++ni) {
      int col = n0 + wc + ni * 16 + (lane & 15);
      int h = col >> 6, dh = col & 63;
      float bv_ = bias[col];
      #pragma unroll
      for (int r = 0; r < 4; ++r) {
        int row = m0 + wr + mi * 16 + (lane >> 4) * 4 + r;
        int b = row >> 11, s = row & 2047;
        out[((size_t)(b * H_ + h) * S_ + s) * DH + dh] =
            (__bf16)((acc[mi][ni][r] + bv_) * scale);
      }
    }
  }
}

// ---------- V transpose: [b][h][s][dh] -> [b][h][dh][s] --------------------
__global__ __launch_bounds__(256) void vtrans(const __bf16* __restrict__ v,
                                              __bf16* __restrict__ vt) {
  __shared__ __bf16 Lt[64 * 64];
  int tid = threadIdx.x;
  int s0 = blockIdx.x * 64;
  int h = blockIdx.y, b = blockIdx.z;
  const __bf16* __restrict__ src = v + ((size_t)(b * H_ + h)) * S_ * DH;
  __bf16* __restrict__ dst = vt + ((size_t)(b * H_ + h)) * DH * S_;
  #pragma unroll
  for (int i = 0; i < 2; ++i) {
    int e = (i * 256 + tid) * 8;
    int s = e >> 6, d0 = e & 63;
    bf16x8 r = *(const bf16x8*)&src[(size_t)(s0 + s) * DH + d0];
    #pragma unroll
    for (int j = 0; j < 8; ++j) {
      int d = d0 + j;
      Lt[d * 64 + (s ^ swz(d))] = r[j];
    }
  }
  __syncthreads();
  #pragma unroll
  for (int i = 0; i < 2; ++i) {
    int e = (i * 256 + tid) * 8;
    int d = e >> 6, sc = e & 63;
    bf16x8 o = *(const bf16x8*)&Lt[d * 64 + (sc ^ swz(d))];
    *(bf16x8*)&dst[(size_t)d * S_ + s0 + sc] = o;
  }
}

// ---------- flash attention: swapped QK^T, paired-tile interleave ----------
// S^T = mfma(A=K, B=Q): lane owns q-col ql=lane&15, kv rows g*4+r per frag.
// Softmax per-tile (log2 domain, defer-max). Helper computes the softmax+PV
// tail for one tile given sfT; QK is done by the caller (to share K frags).
__device__ __forceinline__ void smax_pv(
    f32x4* sfT, f32x4* accO, float& m_reg, float& l_reg,
    const __bf16* __restrict__ Vt, __bf16* __restrict__ Plw,
    int lane, int kv0, int qbase, bool diag) {
  const int g = lane >> 4;
  const int ql = lane & 15;

  if (diag) {
    int qg = qbase + ql;
    #pragma unroll
    for (int f = 0; f < 4; ++f)
      #pragma unroll
      for (int r = 0; r < 4; ++r)
        if (kv0 + f * 16 + g * 4 + r > qg) sfT[f][r] = -1e30f;
  }

  float mx = fmaxf(fmaxf(sfT[0][0], sfT[0][1]), fmaxf(sfT[0][2], sfT[0][3]));
  #pragma unroll
  for (int f = 1; f < 4; ++f)
    mx = fmaxf(mx, fmaxf(fmaxf(sfT[f][0], sfT[f][1]),
                         fmaxf(sfT[f][2], sfT[f][3])));
  mx = fmaxf(mx, __shfl_xor(mx, 16, 64));
  mx = fmaxf(mx, __shfl_xor(mx, 32, 64));

  if (!__all(mx <= m_reg + 11.54f)) {   // defer-max (T13), log2 domain
    float mnew = fmaxf(m_reg, mx);
    float alpha = exp2f(m_reg - mnew);
    m_reg = mnew;
    float ab[4];
    #pragma unroll
    for (int r = 0; r < 4; ++r) ab[r] = __shfl(alpha, g * 4 + r, 16);
    #pragma unroll
    for (int f = 0; f < 4; ++f)
      #pragma unroll
      for (int r = 0; r < 4; ++r) accO[f][r] *= ab[r];
    l_reg *= alpha;
  }

  float rs = 0.f;
  #pragma unroll
  for (int f = 0; f < 4; ++f)
    #pragma unroll
    for (int r = 0; r < 4; ++r) {
      float p = exp2f(sfT[f][r] - m_reg);
      sfT[f][r] = p;
      rs += p;
    }
  rs += __shfl_xor(rs, 16, 64);
  rs += __shfl_xor(rs, 32, 64);
  l_reg += rs;

  const int key = (ql & 7) << 3;
  #pragma unroll
  for (int f = 0; f < 4; ++f)
    #pragma unroll
    for (int r = 0; r < 4; ++r)
      Plw[ql * 64 + ((f * 16 + g * 4 + r) ^ key)] = (__bf16)sfT[f][r];

  __builtin_amdgcn_s_setprio(1);
  #pragma unroll
  for (int kk = 0; kk < 2; ++kk) {
    bf16x8 pa = *(const bf16x8*)&Plw[ql * 64 + ((kk * 32 + g * 8) ^ key)];
    #pragma unroll
    for (int f = 0; f < 4; ++f) {
      int vrow = f * 16 + ql;
      bf16x8 vb = *(const bf16x8*)&Vt[vrow * 64 + ((kk * 32 + g * 8) ^ swz(vrow))];
      accO[f] = __builtin_amdgcn_mfma_f32_16x16x32_bf16(pa, vb, accO[f], 0, 0, 0);
    }
  }
  __builtin_amdgcn_s_setprio(0);
}

__device__ __forceinline__ void attn_out_sw(
    const f32x4* accO, float l_reg, float* __restrict__ out,
    int b, int h, int qbase, int lane) {
  float lr[4];
  #pragma unroll
  for (int r = 0; r < 4; ++r) lr[r] = __shfl(l_reg, (lane >> 4) * 4 + r, 16);
  #pragma unroll
  for (int f = 0; f < 4; ++f) {
    int dh = f * 16 + (lane & 15);
    #pragma unroll
    for (int r = 0; r < 4; ++r) {
      int qg = qbase + (lane >> 4) * 4 + r;
      out[((size_t)(b * S_ + qg)) * D_ + h * DH + dh] = accO[f][r] / lr[r];
    }
  }
}

__global__ __launch_bounds__(256) void attn(
    const __bf16* __restrict__ Q, const __bf16* __restrict__ K,
    const __bf16* __restrict__ VT, float* __restrict__ out) {
  __shared__ __bf16 Kl[64 * 64];        // [kv][dh], swizzled
  __shared__ __bf16 Vt[64 * 64];        // [dh][kv], swizzled
  __shared__ __bf16 Pl[4][2][16 * 64];  // per-wave P, [0]=B tile, [1]=A tile

  int tid = threadIdx.x, lane = tid & 63, w = tid >> 6;
  int bx = blockIdx.x, h = blockIdx.y, b = blockIdx.z;
  int qA0 = bx * 64, qB0 = (NT_ - 1 - bx) * 64;   // paired tiles: i and 31-i
  size_t base = ((size_t)(b * H_ + h)) * S_ * DH;
  const __bf16* __restrict__ Qg = Q + base;
  const __bf16* __restrict__ Kg = K + base;
  const __bf16* __restrict__ VTg = VT + base;     // [dh][s]

  const int g = lane >> 4, ql = lane & 15;

  bf16x8 aqA[2], aqB[2];
  int qra = qA0 + w * 16 + ql, qrb = qB0 + w * 16 + ql;
  #pragma unroll
  for (int kk = 0; kk < 2; ++kk) {
    aqA[kk] = *(const bf16x8*)&Qg[(size_t)qra * DH + kk * 32 + g * 8];
    aqB[kk] = *(const bf16x8*)&Qg[(size_t)qrb * DH + kk * 32 + g * 8];
  }

  f32x4 accA[4] = {}, accB[4] = {};
  float mA = -1e30f, lA = 0.f, mB = -1e30f, lB = 0.f;

  const int ktA = bx, ktB = NT_ - 1 - bx;

  bf16x8 kreg[2], vreg[2];
  #pragma unroll
  for (int i = 0; i < 2; ++i) {
    int e = (i * 256 + tid) * 8;
    kreg[i] = *(const bf16x8*)&Kg[(size_t)(e >> 6) * DH + (e & 63)];
    vreg[i] = *(const bf16x8*)&VTg[(size_t)(e >> 6) * S_ + (e & 63)];
  }

  for (int kt = 0; kt <= ktB; ++kt) {
    int kv0 = kt * 64;
    #pragma unroll
    for (int i = 0; i < 2; ++i) {
      int e = (i * 256 + tid) * 8;
      int rrow = e >> 6, cc = e & 63;
      *(bf16x8*)&Kl[rrow * 64 + (cc ^ swz(rrow))] = kreg[i];
      *(bf16x8*)&Vt[rrow * 64 + (cc ^ swz(rrow))] = vreg[i];
    }
    __syncthreads();

    if (kt < ktB) {
      int kvn = kv0 + 64;
      #pragma unroll
      for (int i = 0; i < 2; ++i) {
        int e = (i * 256 + tid) * 8;
        kreg[i] = *(const bf16x8*)&Kg[(size_t)(kvn + (e >> 6)) * DH + (e & 63)];
        vreg[i] = *(const bf16x8*)&VTg[(size_t)(e >> 6) * S_ + kvn + (e & 63)];
      }
    }

    const bool doA = (kt <= ktA);
    // ---- QK^T for both tiles, sharing each K fragment ----
    f32x4 sB[4], sA[4];
    __builtin_amdgcn_s_setprio(1);
    #pragma unroll
    for (int f = 0; f < 4; ++f) {
      f32x4 zb = {}, za = {};
      int row = f * 16 + ql;
      int sr = swz(row);
      #pragma unroll
      for (int kk = 0; kk < 2; ++kk) {
        bf16x8 ka = *(const bf16x8*)&Kl[row * 64 + ((kk * 32 + g * 8) ^ sr)];
        zb = __builtin_amdgcn_mfma_f32_16x16x32_bf16(ka, aqB[kk], zb, 0, 0, 0);
        if (doA)
          za = __builtin_amdgcn_mfma_f32_16x16x32_bf16(ka, aqA[kk], za, 0, 0, 0);
      }
      sB[f] = zb; sA[f] = za;
    }
    __builtin_amdgcn_s_setprio(0);

    // ---- softmax + PV, B then A (independent chains interleave) ----
    smax_pv(sB, accB, mB, lB, Vt, Pl[w][0], lane, kv0, qB0 + w * 16, kt == ktB);
    if (doA)
      smax_pv(sA, accA, mA, lA, Vt, Pl[w][1], lane, kv0, qA0 + w * 16, kt == ktA);
    __syncthreads();
  }

  attn_out_sw(accA, lA, out, b, h, qA0 + w * 16, lane);
  attn_out_sw(accB, lB, out, b, h, qB0 + w * 16, lane);
}

extern "C" void kernel_launch(void* const* d_in, const int* in_sizes, int n_in,
                              void* d_out, int out_size, void* d_ws, size_t ws_size,
                              hipStream_t stream) {
  const float* x  = (const float*)d_in[0];
  const float* Wq = (const float*)d_in[1];
  const float* bq = (const float*)d_in[2];
  const float* Wk = (const float*)d_in[3];
  const float* bk = (const float*)d_in[4];
  const float* Wv = (const float*)d_in[5];
  const float* bv = (const float*)d_in[6];
  float* out = (float*)d_out;

  __bf16* xb  = (__bf16*)d_ws;             // 8 MB (reused as vt after gemm)
  __bf16* wt  = xb + (size_t)M_ * D_;      // 6 MB
  __bf16* qkv = wt + (size_t)3 * D_ * D_;  // 24 MB
  __bf16* wsq = qkv;
  __bf16* wsk = qkv + (size_t)M_ * D_;
  __bf16* wsv = qkv + (size_t)2 * M_ * D_;
  __bf16* vtg = xb;                        // xb dead after qkv_gemm

  conv_x<<<(M_ * (D_ / 8)) / 256, 256, 0, stream>>>(x, xb);
  conv_w<<<dim3(D_ / 64, D_ / 64, 3), 256, 0, stream>>>(Wq, Wk, Wv, wt);
  qkv_gemm<<<dim3(D_ / BN, M_ / BM, 3), 512, 0, stream>>>(xb, wt, bq, bk, bv, qkv);
  vtrans<<<dim3(S_ / 64, H_, B_), 256, 0, stream>>>(wsv, vtg);
  attn<<<dim3(NT_ / 2, H_, B_), 256, 0, stream>>>(wsq, wsk, vtg, out);
}

// Round 9
// 183.569 us; speedup vs baseline: 1.0668x; 1.0544x over previous
//
#include <hip/hip_runtime.h>
#include <hip/hip_bf16.h>

#define B_ 2
#define S_ 2048
#define D_ 1024
#define H_ 16
#define DH 64
#define M_ (B_*S_)   // 4096
#define NT_ (S_/64)  // 32 q tiles per (b,h)

using bf16x8 = __attribute__((ext_vector_type(8))) __bf16;
using f32x4  = __attribute__((ext_vector_type(4))) float;

__device__ __forceinline__ int swz(int row) { return ((row ^ (row >> 3)) & 7) << 3; }

__device__ __forceinline__ void glds16(const __bf16* g, __bf16* l) {
#if __has_builtin(__builtin_amdgcn_global_load_lds)
  __builtin_amdgcn_global_load_lds(
      (const __attribute__((address_space(1))) unsigned int*)g,
      (__attribute__((address_space(3))) unsigned int*)l, 16, 0, 0);
#else
  *(bf16x8*)l = *(const bf16x8*)g;
#endif
}

// ---------- prep: conv_x (blocks 0..2047) + conv_w (blocks 2048..2815) -----
#define NBX 2048   // conv_x blocks
__global__ __launch_bounds__(256) void prep(
    const float* __restrict__ x, const float* __restrict__ Wq,
    const float* __restrict__ Wk, const float* __restrict__ Wv,
    __bf16* __restrict__ xb, __bf16* __restrict__ wt) {
  int bid = blockIdx.x, tid = threadIdx.x;
  if (bid < NBX) {
    // x fp32 -> bf16, pre-swizzled within 64-col k-groups
    int idx = bid * 256 + tid;
    int m = idx >> 7, k = (idx & 127) * 8;
    float4 a = *(const float4*)&x[(size_t)m * D_ + k];
    float4 b = *(const float4*)&x[(size_t)m * D_ + k + 4];
    bf16x8 o;
    o[0]=(__bf16)a.x; o[1]=(__bf16)a.y; o[2]=(__bf16)a.z; o[3]=(__bf16)a.w;
    o[4]=(__bf16)b.x; o[5]=(__bf16)b.y; o[6]=(__bf16)b.z; o[7]=(__bf16)b.w;
    *(bf16x8*)&xb[(size_t)m * D_ + (k & ~63) + ((k & 63) ^ swz(m))] = o;
    return;
  }
  // W [k][n] fp32 -> Wt [n][k] bf16, pre-swizzled. 256 blocks per z.
  int wb = bid - NBX;
  int z = wb >> 8;
  int kt = (wb & 255) >> 4, nt = wb & 15;
  const float* __restrict__ W = (z == 0) ? Wq : (z == 1) ? Wk : Wv;
  __bf16* __restrict__ Wt = wt + (size_t)z * D_ * D_;
  __shared__ __bf16 Lt[64 * 66];
  int k0 = kt * 64, n0 = nt * 64;
  #pragma unroll
  for (int i = 0; i < 4; ++i) {
    int f4 = i * 256 + tid;
    int r = f4 >> 4, c4 = (f4 & 15) * 4;
    float4 v = *(const float4*)&W[(size_t)(k0 + r) * D_ + n0 + c4];
    Lt[(c4 + 0) * 66 + r] = (__bf16)v.x;
    Lt[(c4 + 1) * 66 + r] = (__bf16)v.y;
    Lt[(c4 + 2) * 66 + r] = (__bf16)v.z;
    Lt[(c4 + 3) * 66 + r] = (__bf16)v.w;
  }
  __syncthreads();
  #pragma unroll
  for (int i = 0; i < 2; ++i) {
    int idx = i * 256 + tid;
    int n = idx >> 3, kc = (idx & 7) * 8;
    int nf = n0 + n;
    bf16x8 o;
    #pragma unroll
    for (int j = 0; j < 8; ++j) o[j] = Lt[n * 66 + kc + j];
    *(bf16x8*)&Wt[(size_t)nf * D_ + k0 + (kc ^ swz(nf))] = o;
  }
}

// ---------- QKV GEMM: 256x256, BK=64, 8 waves, dbuf; XCD swizzle; ----------
// z==2 (V) epilogue writes transposed [b][h][dh][s] directly (kills vtrans).
#define BM 256
#define BN 256
#define BK 64
#define NKT (D_/BK)  // 16
#define NWG 192      // 4 x 16 x 3

__global__ __launch_bounds__(512) void qkv_gemm(
    const __bf16* __restrict__ xb, const __bf16* __restrict__ wt,
    const float* __restrict__ bq, const float* __restrict__ bk,
    const float* __restrict__ bv, __bf16* __restrict__ qk,
    __bf16* __restrict__ vt) {
  // bijective XCD swizzle: NWG=192, 192%8==0, chunk=24 per XCD
  int flat = blockIdx.x;
  int sid = (flat & 7) * (NWG / 8) + (flat >> 3);
  int z = sid >> 6;             // 64 blocks per z (16 my x 4 nx)
  int rem = sid & 63;
  int my = rem >> 2, nx = rem & 3;

  const __bf16* __restrict__ Wt = wt + (size_t)z * D_ * D_;
  const float* __restrict__ bias = (z == 0) ? bq : (z == 1) ? bk : bv;
  const float scale = (z == 0) ? 0.125f : 1.0f;  // 1/sqrt(64) into Q

  __shared__ __bf16 Al[2][BM * BK];
  __shared__ __bf16 Bl[2][BM * BK];

  int tid = threadIdx.x, lane = tid & 63, w = tid >> 6;
  int m0 = my * BM, n0 = nx * BN;
  int wr = (w >> 2) * 128;
  int wc = (w & 3) * 64;

  f32x4 acc[8][4] = {};

#define STAGE(buf, kt)                                                        \
  {                                                                           \
    int k0 = (kt) * BK;                                                       \
    _Pragma("unroll")                                                         \
    for (int r = 0; r < 4; ++r) {                                             \
      int e = (r * 512 + tid) * 8;                                            \
      int row = e >> 6, col = e & 63;                                         \
      glds16(&xb[(size_t)(m0 + row) * D_ + k0 + col], &Al[buf][e]);           \
      glds16(&Wt[(size_t)(n0 + row) * D_ + k0 + col], &Bl[buf][e]);           \
    }                                                                         \
  }

  STAGE(0, 0);
  __syncthreads();

  int cur = 0;
  for (int kt = 0; kt < NKT; ++kt) {
    if (kt + 1 < NKT) STAGE(cur ^ 1, kt + 1);
    #pragma unroll
    for (int kk = 0; kk < 2; ++kk) {
      bf16x8 af[8], bfr[4];
      #pragma unroll
      for (int mi = 0; mi < 8; ++mi) {
        int row = wr + mi * 16 + (lane & 15);
        af[mi] = *(const bf16x8*)&Al[cur][row * 64 +
                 ((kk * 32 + (lane >> 4) * 8) ^ swz(row))];
      }
      #pragma unroll
      for (int ni = 0; ni < 4; ++ni) {
        int col = wc + ni * 16 + (lane & 15);
        bfr[ni] = *(const bf16x8*)&Bl[cur][col * 64 +
                  ((kk * 32 + (lane >> 4) * 8) ^ swz(col))];
      }
      #pragma unroll
      for (int mi = 0; mi < 8; ++mi)
        #pragma unroll
        for (int ni = 0; ni < 4; ++ni)
          acc[mi][ni] = __builtin_amdgcn_mfma_f32_16x16x32_bf16(
              af[mi], bfr[ni], acc[mi][ni], 0, 0, 0);
    }
    __syncthreads();
    cur ^= 1;
  }
#undef STAGE

  // epilogue: C/D layout col=lane&15, row=(lane>>4)*4+r
  if (z < 2) {
    __bf16* __restrict__ out = qk + (size_t)z * M_ * D_;
    #pragma unroll
    for (int mi = 0; mi < 8; ++mi) {
      #pragma unroll
      for (int ni = 0; ni < 4; ++ni) {
        int col = n0 + wc + ni * 16 + (lane & 15);
        int h = col >> 6, dh = col & 63;
        float bv_ = bias[col];
        #pragma unroll
        for (int r = 0; r < 4; ++r) {
          int row = m0 + wr + mi * 16 + (lane >> 4) * 4 + r;
          int b = row >> 11, s = row & 2047;
          out[((size_t)(b * H_ + h) * S_ + s) * DH + dh] =
              (__bf16)((acc[mi][ni][r] + bv_) * scale);
        }
      }
    }
  } else {
    // V: write transposed [b][h][dh][s]
    #pragma unroll
    for (int mi = 0; mi < 8; ++mi) {
      #pragma unroll
      for (int ni = 0; ni < 4; ++ni) {
        int col = n0 + wc + ni * 16 + (lane & 15);
        int h = col >> 6, dh = col & 63;
        float bv_ = bias[col];
        #pragma unroll
        for (int r = 0; r < 4; ++r) {
          int row = m0 + wr + mi * 16 + (lane >> 4) * 4 + r;
          int b = row >> 11, s = row & 2047;
          vt[((size_t)(b * H_ + h) * DH + dh) * S_ + s] =
              (__bf16)(acc[mi][ni][r] + bv_);
        }
      }
    }
  }
}

// ---------- flash attention (R6-exact): swapped QK^T, in-reg softmax -------
__device__ __forceinline__ void attn_tile_sw(
    const bf16x8* aq, f32x4* accO, float& m_reg, float& l_reg,
    const __bf16* __restrict__ Kl, const __bf16* __restrict__ Vt,
    __bf16* __restrict__ Plw, int lane, int kv0, int qbase, bool diag) {
  const int g = lane >> 4;
  const int ql = lane & 15;
  f32x4 sfT[4];
  __builtin_amdgcn_s_setprio(1);
  #pragma unroll
  for (int f = 0; f < 4; ++f) {
    f32x4 zz = {};
    int row = f * 16 + ql;
    int sr = swz(row);
    #pragma unroll
    for (int kk = 0; kk < 2; ++kk) {
      bf16x8 ka = *(const bf16x8*)&Kl[row * 64 + ((kk * 32 + g * 8) ^ sr)];
      zz = __builtin_amdgcn_mfma_f32_16x16x32_bf16(ka, aq[kk], zz, 0, 0, 0);
    }
    sfT[f] = zz;
  }
  __builtin_amdgcn_s_setprio(0);

  if (diag) {
    int qg = qbase + ql;
    #pragma unroll
    for (int f = 0; f < 4; ++f)
      #pragma unroll
      for (int r = 0; r < 4; ++r)
        if (kv0 + f * 16 + g * 4 + r > qg) sfT[f][r] = -1e30f;
  }

  float mx = sfT[0][0];
  #pragma unroll
  for (int f = 0; f < 4; ++f)
    #pragma unroll
    for (int r = 0; r < 4; ++r) mx = fmaxf(mx, sfT[f][r]);
  mx = fmaxf(mx, __shfl_xor(mx, 16, 64));
  mx = fmaxf(mx, __shfl_xor(mx, 32, 64));
  float mnew = fmaxf(m_reg, mx);
  float alpha = __expf(m_reg - mnew);
  m_reg = mnew;
  float rs = 0.f;
  #pragma unroll
  for (int f = 0; f < 4; ++f)
    #pragma unroll
    for (int r = 0; r < 4; ++r) {
      float p = __expf(sfT[f][r] - mnew);
      sfT[f][r] = p;
      rs += p;
    }
  rs += __shfl_xor(rs, 16, 64);
  rs += __shfl_xor(rs, 32, 64);
  l_reg = l_reg * alpha + rs;

  const int key = (ql & 7) << 3;
  #pragma unroll
  for (int f = 0; f < 4; ++f)
    #pragma unroll
    for (int r = 0; r < 4; ++r)
      Plw[ql * 64 + ((f * 16 + g * 4 + r) ^ key)] = (__bf16)sfT[f][r];

  float ab[4];
  #pragma unroll
  for (int r = 0; r < 4; ++r) ab[r] = __shfl(alpha, g * 4 + r, 16);
  #pragma unroll
  for (int f = 0; f < 4; ++f)
    #pragma unroll
    for (int r = 0; r < 4; ++r) accO[f][r] *= ab[r];

  __builtin_amdgcn_s_setprio(1);
  #pragma unroll
  for (int kk = 0; kk < 2; ++kk) {
    bf16x8 pa = *(const bf16x8*)&Plw[ql * 64 + ((kk * 32 + g * 8) ^ key)];
    #pragma unroll
    for (int f = 0; f < 4; ++f) {
      int vrow = f * 16 + ql;
      bf16x8 vb = *(const bf16x8*)&Vt[vrow * 64 + ((kk * 32 + g * 8) ^ swz(vrow))];
      accO[f] = __builtin_amdgcn_mfma_f32_16x16x32_bf16(pa, vb, accO[f], 0, 0, 0);
    }
  }
  __builtin_amdgcn_s_setprio(0);
}

__device__ __forceinline__ void attn_out_sw(
    const f32x4* accO, float l_reg, float* __restrict__ out,
    int b, int h, int qbase, int lane) {
  float lr[4];
  #pragma unroll
  for (int r = 0; r < 4; ++r) lr[r] = __shfl(l_reg, (lane >> 4) * 4 + r, 16);
  #pragma unroll
  for (int f = 0; f < 4; ++f) {
    int dh = f * 16 + (lane & 15);
    #pragma unroll
    for (int r = 0; r < 4; ++r) {
      int qg = qbase + (lane >> 4) * 4 + r;
      out[((size_t)(b * S_ + qg)) * D_ + h * DH + dh] = accO[f][r] / lr[r];
    }
  }
}

__global__ __launch_bounds__(256) void attn(
    const __bf16* __restrict__ Q, const __bf16* __restrict__ K,
    const __bf16* __restrict__ VT, float* __restrict__ out) {
  __shared__ __bf16 Kl[64 * 64];
  __shared__ __bf16 Vt[64 * 64];
  __shared__ __bf16 Pl[4][16 * 64];

  int tid = threadIdx.x, lane = tid & 63, w = tid >> 6;
  int bx = blockIdx.x, h = blockIdx.y, b = blockIdx.z;
  int qA0 = bx * 64, qB0 = (NT_ - 1 - bx) * 64;
  size_t base = ((size_t)(b * H_ + h)) * S_ * DH;
  const __bf16* __restrict__ Qg = Q + base;
  const __bf16* __restrict__ Kg = K + base;
  const __bf16* __restrict__ VTg = VT + base;   // [dh][s]

  const int g = lane >> 4, ql = lane & 15;

  bf16x8 aqA[2], aqB[2];
  int qra = qA0 + w * 16 + ql, qrb = qB0 + w * 16 + ql;
  #pragma unroll
  for (int kk = 0; kk < 2; ++kk) {
    aqA[kk] = *(const bf16x8*)&Qg[(size_t)qra * DH + kk * 32 + g * 8];
    aqB[kk] = *(const bf16x8*)&Qg[(size_t)qrb * DH + kk * 32 + g * 8];
  }

  f32x4 accA[4] = {}, accB[4] = {};
  float mA = -1e30f, lA = 0.f, mB = -1e30f, lB = 0.f;

  const int ktA = bx, ktB = NT_ - 1 - bx;

  bf16x8 kreg[2], vreg[2];
  #pragma unroll
  for (int i = 0; i < 2; ++i) {
    int e = (i * 256 + tid) * 8;
    kreg[i] = *(const bf16x8*)&Kg[(size_t)(e >> 6) * DH + (e & 63)];
    vreg[i] = *(const bf16x8*)&VTg[(size_t)(e >> 6) * S_ + (e & 63)];
  }

  for (int kt = 0; kt <= ktB; ++kt) {
    int kv0 = kt * 64;
    #pragma unroll
    for (int i = 0; i < 2; ++i) {
      int e = (i * 256 + tid) * 8;
      int rrow = e >> 6, cc = e & 63;
      *(bf16x8*)&Kl[rrow * 64 + (cc ^ swz(rrow))] = kreg[i];
      *(bf16x8*)&Vt[rrow * 64 + (cc ^ swz(rrow))] = vreg[i];
    }
    __syncthreads();

    if (kt < ktB) {
      int kvn = kv0 + 64;
      #pragma unroll
      for (int i = 0; i < 2; ++i) {
        int e = (i * 256 + tid) * 8;
        kreg[i] = *(const bf16x8*)&Kg[(size_t)(kvn + (e >> 6)) * DH + (e & 63)];
        vreg[i] = *(const bf16x8*)&VTg[(size_t)(e >> 6) * S_ + kvn + (e & 63)];
      }
    }

    attn_tile_sw(aqB, accB, mB, lB, Kl, Vt, Pl[w], lane, kv0, qB0 + w * 16,
                 kt == ktB);
    if (kt <= ktA)
      attn_tile_sw(aqA, accA, mA, lA, Kl, Vt, Pl[w], lane, kv0, qA0 + w * 16,
                   kt == ktA);
    __syncthreads();
  }

  attn_out_sw(accA, lA, out, b, h, qA0 + w * 16, lane);
  attn_out_sw(accB, lB, out, b, h, qB0 + w * 16, lane);
}

extern "C" void kernel_launch(void* const* d_in, const int* in_sizes, int n_in,
                              void* d_out, int out_size, void* d_ws, size_t ws_size,
                              hipStream_t stream) {
  const float* x  = (const float*)d_in[0];
  const float* Wq = (const float*)d_in[1];
  const float* bq = (const float*)d_in[2];
  const float* Wk = (const float*)d_in[3];
  const float* bk = (const float*)d_in[4];
  const float* Wv = (const float*)d_in[5];
  const float* bv = (const float*)d_in[6];
  float* out = (float*)d_out;

  __bf16* xb  = (__bf16*)d_ws;             // 8 MB
  __bf16* wt  = xb + (size_t)M_ * D_;      // 6 MB
  __bf16* qkv = wt + (size_t)3 * D_ * D_;  // 24 MB: Q, K, V^T
  __bf16* wsq = qkv;
  __bf16* wsk = qkv + (size_t)M_ * D_;
  __bf16* vtg = qkv + (size_t)2 * M_ * D_; // V written transposed by gemm

  prep<<<NBX + 768, 256, 0, stream>>>(x, Wq, Wk, Wv, xb, wt);
  qkv_gemm<<<NWG, 512, 0, stream>>>(xb, wt, bq, bk, bv, qkv, vtg);
  attn<<<dim3(NT_ / 2, H_, B_), 256, 0, stream>>>(wsq, wsk, vtg, out);
}

// Round 10
// 180.535 us; speedup vs baseline: 1.0847x; 1.0168x over previous
//
#include <hip/hip_runtime.h>
#include <hip/hip_bf16.h>

#define B_ 2
#define S_ 2048
#define D_ 1024
#define H_ 16
#define DH 64
#define M_ (B_*S_)   // 4096
#define NT_ (S_/64)  // 32 q tiles per (b,h)

using bf16x8 = __attribute__((ext_vector_type(8))) __bf16;
using bf16x4 = __attribute__((ext_vector_type(4))) __bf16;
using f32x4  = __attribute__((ext_vector_type(4))) float;

__device__ __forceinline__ int swz(int row) { return ((row ^ (row >> 3)) & 7) << 3; }

__device__ __forceinline__ void glds16(const __bf16* g, __bf16* l) {
#if __has_builtin(__builtin_amdgcn_global_load_lds)
  __builtin_amdgcn_global_load_lds(
      (const __attribute__((address_space(1))) unsigned int*)g,
      (__attribute__((address_space(3))) unsigned int*)l, 16, 0, 0);
#else
  *(bf16x8*)l = *(const bf16x8*)g;
#endif
}

// ---------- prep: conv_x (blocks 0..2047) + conv_w (blocks 2048..2815) -----
#define NBX 2048
__global__ __launch_bounds__(256) void prep(
    const float* __restrict__ x, const float* __restrict__ Wq,
    const float* __restrict__ Wk, const float* __restrict__ Wv,
    __bf16* __restrict__ xb, __bf16* __restrict__ wt) {
  int bid = blockIdx.x, tid = threadIdx.x;
  if (bid < NBX) {
    int idx = bid * 256 + tid;
    int m = idx >> 7, k = (idx & 127) * 8;
    float4 a = *(const float4*)&x[(size_t)m * D_ + k];
    float4 b = *(const float4*)&x[(size_t)m * D_ + k + 4];
    bf16x8 o;
    o[0]=(__bf16)a.x; o[1]=(__bf16)a.y; o[2]=(__bf16)a.z; o[3]=(__bf16)a.w;
    o[4]=(__bf16)b.x; o[5]=(__bf16)b.y; o[6]=(__bf16)b.z; o[7]=(__bf16)b.w;
    *(bf16x8*)&xb[(size_t)m * D_ + (k & ~63) + ((k & 63) ^ swz(m))] = o;
    return;
  }
  int wb = bid - NBX;
  int z = wb >> 8;
  int kt = (wb & 255) >> 4, nt = wb & 15;
  const float* __restrict__ W = (z == 0) ? Wq : (z == 1) ? Wk : Wv;
  __bf16* __restrict__ Wt = wt + (size_t)z * D_ * D_;
  __shared__ __bf16 Lt[64 * 66];
  int k0 = kt * 64, n0 = nt * 64;
  #pragma unroll
  for (int i = 0; i < 4; ++i) {
    int f4 = i * 256 + tid;
    int r = f4 >> 4, c4 = (f4 & 15) * 4;
    float4 v = *(const float4*)&W[(size_t)(k0 + r) * D_ + n0 + c4];
    Lt[(c4 + 0) * 66 + r] = (__bf16)v.x;
    Lt[(c4 + 1) * 66 + r] = (__bf16)v.y;
    Lt[(c4 + 2) * 66 + r] = (__bf16)v.z;
    Lt[(c4 + 3) * 66 + r] = (__bf16)v.w;
  }
  __syncthreads();
  #pragma unroll
  for (int i = 0; i < 2; ++i) {
    int idx = i * 256 + tid;
    int n = idx >> 3, kc = (idx & 7) * 8;
    int nf = n0 + n;
    bf16x8 o;
    #pragma unroll
    for (int j = 0; j < 8; ++j) o[j] = Lt[n * 66 + kc + j];
    *(bf16x8*)&Wt[(size_t)nf * D_ + k0 + (kc ^ swz(nf))] = o;
  }
}

// ---------- QKV GEMM: 256x256, BK=64, 8 waves, 4-phase counted-vmcnt -------
#define BM 256
#define BN 256
#define BK 64
#define NKT (D_/BK)  // 16
#define NWG 192

__global__ __launch_bounds__(512) void qkv_gemm(
    const __bf16* __restrict__ xb, const __bf16* __restrict__ wt,
    const float* __restrict__ bq, const float* __restrict__ bk,
    const float* __restrict__ bv, __bf16* __restrict__ qk,
    __bf16* __restrict__ vt) {
  int flat = blockIdx.x;
  int sid = (flat & 7) * (NWG / 8) + (flat >> 3);   // bijective XCD swizzle
  int z = sid >> 6;
  int rem = sid & 63;
  int my = rem >> 2, nx = rem & 3;

  const __bf16* __restrict__ Wt = wt + (size_t)z * D_ * D_;
  const float* __restrict__ bias = (z == 0) ? bq : (z == 1) ? bk : bv;
  // Q gets 1/sqrt(64) * log2(e): attn softmax runs in exp2 domain
  const float scale = (z == 0) ? 0.18033688f : 1.0f;

  __shared__ __bf16 SB[4][BM * BK];   // [0..1]=A dbuf, [2..3]=B dbuf; 128KB

  int tid = threadIdx.x, lane = tid & 63, w = tid >> 6;
  const int g = lane >> 4, ql = lane & 15;
  int m0 = my * BM, n0 = nx * BN;
  int wr = (w >> 2) * 128;
  int wc = (w & 3) * 64;

  f32x4 acc[8][4] = {};
  bf16x8 bfr[4];

  // stage calls 2p, 2p+1 of tile kt into buffer buf (c<4: A band c; else B)
#define STAGE2(buf, kt, p)                                                    \
  {                                                                           \
    int k0 = (kt) * BK;                                                       \
    _Pragma("unroll")                                                         \
    for (int q = 0; q < 2; ++q) {                                             \
      int c = 2 * (p) + q;                                                    \
      int e = ((c & 3) * 512 + tid) * 8;                                      \
      int row = e >> 6, col = e & 63;                                         \
      if (c < 4) glds16(&xb[(size_t)(m0 + row) * D_ + k0 + col], &SB[buf][e]);\
      else glds16(&Wt[(size_t)(n0 + row) * D_ + k0 + col], &SB[2 + (buf)][e]);\
    }                                                                         \
  }

#define DSB(buf, kk)                                                          \
  {                                                                           \
    _Pragma("unroll")                                                         \
    for (int ni = 0; ni < 4; ++ni) {                                          \
      int col = wc + ni * 16 + ql;                                            \
      bfr[ni] = *(const bf16x8*)&SB[2 + (buf)][col * 64 +                     \
                (((kk) * 32 + g * 8) ^ swz(col))];                            \
    }                                                                         \
  }

#define DSA4(buf, kk, mh, af)                                                 \
  {                                                                           \
    _Pragma("unroll")                                                         \
    for (int mi = 0; mi < 4; ++mi) {                                          \
      int row = wr + ((mh) * 4 + mi) * 16 + ql;                               \
      af[mi] = *(const bf16x8*)&SB[buf][row * 64 +                            \
               (((kk) * 32 + g * 8) ^ swz(row))];                             \
    }                                                                         \
  }

#define MFMA16(af, mh)                                                        \
  {                                                                           \
    __builtin_amdgcn_s_setprio(1);                                            \
    _Pragma("unroll")                                                         \
    for (int mi = 0; mi < 4; ++mi)                                            \
      _Pragma("unroll")                                                       \
      for (int ni = 0; ni < 4; ++ni)                                          \
        acc[(mh) * 4 + mi][ni] = __builtin_amdgcn_mfma_f32_16x16x32_bf16(     \
            af[mi], bfr[ni], acc[(mh) * 4 + mi][ni], 0, 0, 0);                \
    __builtin_amdgcn_s_setprio(0);                                            \
  }

  // prologue: stage tile 0 fully (8 loads)
  #pragma unroll
  for (int p = 0; p < 4; ++p) STAGE2(0, 0, p);

  for (int t = 0; t < NKT; ++t) {
    int cb = t & 1, nb = cb ^ 1;
    bool pf = (t + 1 < NKT);
    bf16x8 af[4];
    // ---- P0: issue A-band0,1(t+1); wait old tile; barrier; kk0 mi0-3 ----
    if (pf) STAGE2(nb, t + 1, 0);
    __builtin_amdgcn_sched_barrier(0);
    if (pf) { asm volatile("s_waitcnt vmcnt(2)" ::: "memory"); }
    else    { asm volatile("s_waitcnt vmcnt(0)" ::: "memory"); }
    __builtin_amdgcn_sched_barrier(0);
    __builtin_amdgcn_s_barrier();
    __builtin_amdgcn_sched_barrier(0);
    DSB(cb, 0);
    DSA4(cb, 0, 0, af);
    MFMA16(af, 0);
    // ---- P1: issue A-band2,3; kk0 mi4-7 ----
    if (pf) STAGE2(nb, t + 1, 1);
    DSA4(cb, 0, 1, af);
    __builtin_amdgcn_s_barrier();
    MFMA16(af, 1);
    // ---- P2: issue B-band0,1; kk1 mi0-3 ----
    if (pf) STAGE2(nb, t + 1, 2);
    DSB(cb, 1);
    DSA4(cb, 1, 0, af);
    __builtin_amdgcn_s_barrier();
    MFMA16(af, 0);
    // ---- P3: issue B-band2,3; kk1 mi4-7 ----
    if (pf) STAGE2(nb, t + 1, 3);
    DSA4(cb, 1, 1, af);
    __builtin_amdgcn_s_barrier();
    MFMA16(af, 1);
  }
  __syncthreads();   // full drain before LDS reuse in epilogue
#undef STAGE2
#undef DSB
#undef DSA4
#undef MFMA16

  // ---- epilogue via LDS transpose; all stores b128-coalesced ----
  __bf16* Lt = &SB[0][0];   // 128KB = full 256x256 bf16 tile
  const int b = m0 >> 11;
  const int sbase = m0 & 2047;
  if (z == 2) {
    // layout Lt[n][m ^ key(n)]; V^T out [b][h][dh][s]
    #pragma unroll
    for (int mi = 0; mi < 8; ++mi) {
      #pragma unroll
      for (int ni = 0; ni < 4; ++ni) {
        int nl = wc + ni * 16 + ql;
        int ml = wr + mi * 16 + g * 4;
        float bv_ = bias[n0 + nl];
        bf16x4 p4;
        #pragma unroll
        for (int r = 0; r < 4; ++r) p4[r] = (__bf16)(acc[mi][ni][r] + bv_);
        *(bf16x4*)&Lt[nl * 256 + (ml ^ ((nl & 7) << 3))] = p4;
      }
    }
    __syncthreads();
    #pragma unroll
    for (int i = 0; i < 16; ++i) {
      int gi = i * 512 + tid;
      int n = gi >> 5, mg = (gi & 31) * 8;
      bf16x8 v = *(const bf16x8*)&Lt[n * 256 + (mg ^ ((n & 7) << 3))];
      int col = n0 + n, hh = col >> 6, dh = col & 63;
      *(bf16x8*)&vt[((size_t)(b * H_ + hh) * DH + dh) * S_ + sbase + mg] = v;
    }
  } else {
    // layout Lt[m][n ^ key(m)]; out [b][h][s][dh]
    __bf16* __restrict__ out = qk + (size_t)z * M_ * D_;
    #pragma unroll
    for (int mi = 0; mi < 8; ++mi) {
      #pragma unroll
      for (int ni = 0; ni < 4; ++ni) {
        int nl = wc + ni * 16 + ql;
        float bv_ = bias[n0 + nl];
        #pragma unroll
        for (int r = 0; r < 4; ++r) {
          int ml = wr + mi * 16 + g * 4 + r;
          Lt[ml * 256 + (nl ^ ((ml & 7) << 3))] =
              (__bf16)((acc[mi][ni][r] + bv_) * scale);
        }
      }
    }
    __syncthreads();
    #pragma unroll
    for (int i = 0; i < 16; ++i) {
      int gi = i * 512 + tid;
      int ml = gi >> 5, rest = gi & 31;
      int hh = rest >> 3, cg = (rest & 7) * 8;
      int n = hh * 64 + cg;
      bf16x8 v = *(const bf16x8*)&Lt[ml * 256 + (n ^ ((ml & 7) << 3))];
      int col = n0 + n, ho = col >> 6, dh = col & 63;
      *(bf16x8*)&out[((size_t)(b * H_ + ho) * S_ + sbase + ml) * DH + dh] = v;
    }
  }
}

// ---------- flash attention: swapped QK^T, exp2 softmax --------------------
__device__ __forceinline__ void attn_tile_sw(
    const bf16x8* aq, f32x4* accO, float& m_reg, float& l_reg,
    const __bf16* __restrict__ Kl, const __bf16* __restrict__ Vt,
    __bf16* __restrict__ Plw, int lane, int kv0, int qbase, bool diag) {
  const int g = lane >> 4;
  const int ql = lane & 15;
  f32x4 sfT[4];
  __builtin_amdgcn_s_setprio(1);
  #pragma unroll
  for (int f = 0; f < 4; ++f) {
    f32x4 zz = {};
    int row = f * 16 + ql;
    int sr = swz(row);
    #pragma unroll
    for (int kk = 0; kk < 2; ++kk) {
      bf16x8 ka = *(const bf16x8*)&Kl[row * 64 + ((kk * 32 + g * 8) ^ sr)];
      zz = __builtin_amdgcn_mfma_f32_16x16x32_bf16(ka, aq[kk], zz, 0, 0, 0);
    }
    sfT[f] = zz;
  }
  __builtin_amdgcn_s_setprio(0);

  if (diag) {
    int qg = qbase + ql;
    #pragma unroll
    for (int f = 0; f < 4; ++f)
      #pragma unroll
      for (int r = 0; r < 4; ++r)
        if (kv0 + f * 16 + g * 4 + r > qg) sfT[f][r] = -1e30f;
  }

  float mx = sfT[0][0];
  #pragma unroll
  for (int f = 0; f < 4; ++f)
    #pragma unroll
    for (int r = 0; r < 4; ++r) mx = fmaxf(mx, sfT[f][r]);
  mx = fmaxf(mx, __shfl_xor(mx, 16, 64));
  mx = fmaxf(mx, __shfl_xor(mx, 32, 64));
  float mnew = fmaxf(m_reg, mx);
  float alpha = exp2f(m_reg - mnew);
  m_reg = mnew;
  float rs = 0.f;
  #pragma unroll
  for (int f = 0; f < 4; ++f)
    #pragma unroll
    for (int r = 0; r < 4; ++r) {
      float p = exp2f(sfT[f][r] - mnew);
      sfT[f][r] = p;
      rs += p;
    }
  rs += __shfl_xor(rs, 16, 64);
  rs += __shfl_xor(rs, 32, 64);
  l_reg = l_reg * alpha + rs;

  const int key = (ql & 7) << 3;
  #pragma unroll
  for (int f = 0; f < 4; ++f)
    #pragma unroll
    for (int r = 0; r < 4; ++r)
      Plw[ql * 64 + ((f * 16 + g * 4 + r) ^ key)] = (__bf16)sfT[f][r];

  float ab[4];
  #pragma unroll
  for (int r = 0; r < 4; ++r) ab[r] = __shfl(alpha, g * 4 + r, 16);
  #pragma unroll
  for (int f = 0; f < 4; ++f)
    #pragma unroll
    for (int r = 0; r < 4; ++r) accO[f][r] *= ab[r];

  __builtin_amdgcn_s_setprio(1);
  #pragma unroll
  for (int kk = 0; kk < 2; ++kk) {
    bf16x8 pa = *(const bf16x8*)&Plw[ql * 64 + ((kk * 32 + g * 8) ^ key)];
    #pragma unroll
    for (int f = 0; f < 4; ++f) {
      int vrow = f * 16 + ql;
      bf16x8 vb = *(const bf16x8*)&Vt[vrow * 64 + ((kk * 32 + g * 8) ^ swz(vrow))];
      accO[f] = __builtin_amdgcn_mfma_f32_16x16x32_bf16(pa, vb, accO[f], 0, 0, 0);
    }
  }
  __builtin_amdgcn_s_setprio(0);
}

__device__ __forceinline__ void attn_out_sw(
    const f32x4* accO, float l_reg, float* __restrict__ out,
    int b, int h, int qbase, int lane) {
  float lr[4];
  #pragma unroll
  for (int r = 0; r < 4; ++r) lr[r] = __shfl(l_reg, (lane >> 4) * 4 + r, 16);
  #pragma unroll
  for (int f = 0; f < 4; ++f) {
    int dh = f * 16 + (lane & 15);
    #pragma unroll
    for (int r = 0; r < 4; ++r) {
      int qg = qbase + (lane >> 4) * 4 + r;
      out[((size_t)(b * S_ + qg)) * D_ + h * DH + dh] = accO[f][r] / lr[r];
    }
  }
}

__global__ __launch_bounds__(256) void attn(
    const __bf16* __restrict__ Q, const __bf16* __restrict__ K,
    const __bf16* __restrict__ VT, float* __restrict__ out) {
  __shared__ __bf16 Kl[64 * 64];
  __shared__ __bf16 Vt[64 * 64];
  __shared__ __bf16 Pl[4][16 * 64];

  int tid = threadIdx.x, lane = tid & 63, w = tid >> 6;
  int bx = blockIdx.x, h = blockIdx.y, b = blockIdx.z;
  int qA0 = bx * 64, qB0 = (NT_ - 1 - bx) * 64;
  size_t base = ((size_t)(b * H_ + h)) * S_ * DH;
  const __bf16* __restrict__ Qg = Q + base;
  const __bf16* __restrict__ Kg = K + base;
  const __bf16* __restrict__ VTg = VT + base;

  const int g = lane >> 4, ql = lane & 15;

  bf16x8 aqA[2], aqB[2];
  int qra = qA0 + w * 16 + ql, qrb = qB0 + w * 16 + ql;
  #pragma unroll
  for (int kk = 0; kk < 2; ++kk) {
    aqA[kk] = *(const bf16x8*)&Qg[(size_t)qra * DH + kk * 32 + g * 8];
    aqB[kk] = *(const bf16x8*)&Qg[(size_t)qrb * DH + kk * 32 + g * 8];
  }

  f32x4 accA[4] = {}, accB[4] = {};
  float mA = -1e30f, lA = 0.f, mB = -1e30f, lB = 0.f;

  const int ktA = bx, ktB = NT_ - 1 - bx;

  bf16x8 kreg[2], vreg[2];
  #pragma unroll
  for (int i = 0; i < 2; ++i) {
    int e = (i * 256 + tid) * 8;
    kreg[i] = *(const bf16x8*)&Kg[(size_t)(e >> 6) * DH + (e & 63)];
    vreg[i] = *(const bf16x8*)&VTg[(size_t)(e >> 6) * S_ + (e & 63)];
  }

  for (int kt = 0; kt <= ktB; ++kt) {
    int kv0 = kt * 64;
    #pragma unroll
    for (int i = 0; i < 2; ++i) {
      int e = (i * 256 + tid) * 8;
      int rrow = e >> 6, cc = e & 63;
      *(bf16x8*)&Kl[rrow * 64 + (cc ^ swz(rrow))] = kreg[i];
      *(bf16x8*)&Vt[rrow * 64 + (cc ^ swz(rrow))] = vreg[i];
    }
    __syncthreads();

    if (kt < ktB) {
      int kvn = kv0 + 64;
      #pragma unroll
      for (int i = 0; i < 2; ++i) {
        int e = (i * 256 + tid) * 8;
        kreg[i] = *(const bf16x8*)&Kg[(size_t)(kvn + (e >> 6)) * DH + (e & 63)];
        vreg[i] = *(const bf16x8*)&VTg[(size_t)(e >> 6) * S_ + kvn + (e & 63)];
      }
    }

    attn_tile_sw(aqB, accB, mB, lB, Kl, Vt, Pl[w], lane, kv0, qB0 + w * 16,
                 kt == ktB);
    if (kt <= ktA)
      attn_tile_sw(aqA, accA, mA, lA, Kl, Vt, Pl[w], lane, kv0, qA0 + w * 16,
                   kt == ktA);
    __syncthreads();
  }

  attn_out_sw(accA, lA, out, b, h, qA0 + w * 16, lane);
  attn_out_sw(accB, lB, out, b, h, qB0 + w * 16, lane);
}

extern "C" void kernel_launch(void* const* d_in, const int* in_sizes, int n_in,
                              void* d_out, int out_size, void* d_ws, size_t ws_size,
                              hipStream_t stream) {
  const float* x  = (const float*)d_in[0];
  const float* Wq = (const float*)d_in[1];
  const float* bq = (const float*)d_in[2];
  const float* Wk = (const float*)d_in[3];
  const float* bk = (const float*)d_in[4];
  const float* Wv = (const float*)d_in[5];
  const float* bv = (const float*)d_in[6];
  float* out = (float*)d_out;

  __bf16* xb  = (__bf16*)d_ws;             // 8 MB
  __bf16* wt  = xb + (size_t)M_ * D_;      // 6 MB
  __bf16* qkv = wt + (size_t)3 * D_ * D_;  // 24 MB: Q, K, V^T
  __bf16* wsq = qkv;
  __bf16* wsk = qkv + (size_t)M_ * D_;
  __bf16* vtg = qkv + (size_t)2 * M_ * D_;

  prep<<<NBX + 768, 256, 0, stream>>>(x, Wq, Wk, Wv, xb, wt);
  qkv_gemm<<<NWG, 512, 0, stream>>>(xb, wt, bq, bk, bv, qkv, vtg);
  attn<<<dim3(NT_ / 2, H_, B_), 256, 0, stream>>>(wsq, wsk, vtg, out);
}